// Round 1
// baseline (198.659 us; speedup 1.0000x reference)
//
#include <hip/hip_runtime.h>
#include <hip/hip_bf16.h>

// TTT-MLP fused pipeline for MI355X (gfx950).
// ref: out = LN( relu(x@W1^T + b1) @ W2^T + b2 ) @ Wo^T + bo )   [per token]
// Strategy: cast to bf16, three m97-structure MFMA GEMMs (B^T input form),
// wave-per-row LayerNorm in place on d_out.

#define HIDDEN 768
#define INNER  512

typedef __bf16 bf16_t;
typedef bf16_t bf16x8 __attribute__((ext_vector_type(8)));
typedef bf16_t bf16x4 __attribute__((ext_vector_type(4)));
typedef float  f32x4  __attribute__((ext_vector_type(4)));

__device__ __forceinline__ void async16(const void* g, void* lds) {
  __builtin_amdgcn_global_load_lds(
      (const __attribute__((address_space(1))) unsigned int*)g,
      (__attribute__((address_space(3))) unsigned int*)lds, 16, 0, 0);
}

// ---------------------------------------------------------------- cast f32->bf16
__global__ __launch_bounds__(256) void cast_bf16(const float4* __restrict__ in,
                                                 bf16x4* __restrict__ out, int n4) {
  int stride = gridDim.x * blockDim.x;
  for (int i = blockIdx.x * blockDim.x + threadIdx.x; i < n4; i += stride) {
    float4 v = in[i];
    bf16x4 o;
    o[0] = (bf16_t)v.x; o[1] = (bf16_t)v.y; o[2] = (bf16_t)v.z; o[3] = (bf16_t)v.w;
    out[i] = o;
  }
}

// ---------------------------------------------------------------- GEMM (A[M,K] x Bt[N,K])
// MODE 0: bias+relu -> bf16 ; MODE 1: bias -> bf16 ; MODE 2: bias -> f32
// 128x128 tile, BK=64, 4 waves (2x2), each wave 64x64 via 4x4 of 16x16x32 MFMA.
template <int N_, int K_, int MODE>
__global__ __launch_bounds__(256, 2)
void gemm_bt(const bf16_t* __restrict__ A, const bf16_t* __restrict__ Bt,
             const float* __restrict__ bias, void* __restrict__ Cout) {
  constexpr int NT = N_ / 128;
  __shared__ __align__(16) bf16_t As[128 * 64];
  __shared__ __align__(16) bf16_t Bs[128 * 64];

  // XCD-aware swizzle (grid % 8 == 0 for all our shapes)
  const int nwg = gridDim.x;
  const int per = nwg >> 3;
  const int bid = blockIdx.x;
  const int nb  = (bid & 7) * per + (bid >> 3);
  const int m0 = (nb / NT) * 128;
  const int n0 = (nb % NT) * 128;

  const int w  = threadIdx.x >> 6;   // wave 0..3
  const int l  = threadIdx.x & 63;
  const int wr = w >> 1, wc = w & 1; // wave grid 2x2
  const int fr = l & 15, fq = l >> 4;

  f32x4 acc[4][4] = {};

  for (int k0 = 0; k0 < K_; k0 += 64) {
    __syncthreads();
    // stage A tile: 128 rows x 64 cols bf16 = 16KB; 16 wave-issues of 1KB
#pragma unroll
    for (int i = 0; i < 4; ++i) {
      const int base = (i * 4 + w) * 1024;      // byte offset in As
      const int off  = base + l * 16;
      const int row  = off >> 7;                // 128B per row
      const int kb   = off & 127;               // byte-in-row
      async16(A + (size_t)(m0 + row) * K_ + k0 + (kb >> 1), (char*)As + base);
    }
#pragma unroll
    for (int i = 0; i < 4; ++i) {
      const int base = (i * 4 + w) * 1024;
      const int off  = base + l * 16;
      const int row  = off >> 7;
      const int kb   = off & 127;
      async16(Bt + (size_t)(n0 + row) * K_ + k0 + (kb >> 1), (char*)Bs + base);
    }
    __syncthreads();   // drains vmcnt before barrier (compiler-inserted)

#pragma unroll
    for (int kk = 0; kk < 2; ++kk) {
      bf16x8 ax[4], bx[4];
#pragma unroll
      for (int m = 0; m < 4; ++m) {
        const int row = wr * 64 + m * 16 + fr;
        ax[m] = *(const bf16x8*)((const char*)As + row * 128 + kk * 64 + fq * 16);
      }
#pragma unroll
      for (int n = 0; n < 4; ++n) {
        const int row = wc * 64 + n * 16 + fr;
        bx[n] = *(const bf16x8*)((const char*)Bs + row * 128 + kk * 64 + fq * 16);
      }
#pragma unroll
      for (int m = 0; m < 4; ++m)
#pragma unroll
        for (int n = 0; n < 4; ++n)
          acc[m][n] = __builtin_amdgcn_mfma_f32_16x16x32_bf16(ax[m], bx[n], acc[m][n], 0, 0, 0);
    }
  }

  // epilogue: D lane mapping col = lane&15, row = (lane>>4)*4 + j   [m89-verified]
  const int orow0 = m0 + wr * 64 + fq * 4;
  const int ocol0 = n0 + wc * 64 + fr;
#pragma unroll
  for (int n = 0; n < 4; ++n) {
    const int col = ocol0 + n * 16;
    const float bv = bias[col];
#pragma unroll
    for (int m = 0; m < 4; ++m) {
#pragma unroll
      for (int j = 0; j < 4; ++j) {
        const int row = orow0 + m * 16 + j;
        float v = acc[m][n][j] + bv;
        if (MODE == 0) v = fmaxf(v, 0.f);
        if (MODE == 2) ((float*)Cout)[(size_t)row * N_ + col] = v;
        else           ((bf16_t*)Cout)[(size_t)row * N_ + col] = (bf16_t)v;
      }
    }
  }
}

// ---------------------------------------------------------------- LayerNorm (in place, wave per row)
__global__ __launch_bounds__(256) void ln_rows(float* __restrict__ io,
                                               const float* __restrict__ gamma,
                                               const float* __restrict__ beta, int rows) {
  const int wid = blockIdx.x * 4 + (threadIdx.x >> 6);
  const int l   = threadIdx.x & 63;
  if (wid >= rows) return;
  float* r = io + (size_t)wid * HIDDEN;
  float4 v[3];
#pragma unroll
  for (int i = 0; i < 3; ++i) v[i] = ((const float4*)r)[i * 64 + l];
  float s = 0.f, q = 0.f;
#pragma unroll
  for (int i = 0; i < 3; ++i) {
    s += v[i].x + v[i].y + v[i].z + v[i].w;
    q += v[i].x * v[i].x + v[i].y * v[i].y + v[i].z * v[i].z + v[i].w * v[i].w;
  }
#pragma unroll
  for (int o = 32; o; o >>= 1) {
    s += __shfl_xor(s, o, 64);
    q += __shfl_xor(q, o, 64);
  }
  const float mu  = s * (1.0f / HIDDEN);
  const float var = fmaxf(q * (1.0f / HIDDEN) - mu * mu, 0.f);
  const float inv = rsqrtf(var + 1e-5f);
#pragma unroll
  for (int i = 0; i < 3; ++i) {
    float4 g = ((const float4*)gamma)[i * 64 + l];
    float4 b = ((const float4*)beta)[i * 64 + l];
    float4 o;
    o.x = (v[i].x - mu) * inv * g.x + b.x;
    o.y = (v[i].y - mu) * inv * g.y + b.y;
    o.z = (v[i].z - mu) * inv * g.z + b.z;
    o.w = (v[i].w - mu) * inv * g.w + b.w;
    ((float4*)r)[i * 64 + l] = o;
  }
}

// ---------------------------------------------------------------- launch
extern "C" void kernel_launch(void* const* d_in, const int* in_sizes, int n_in,
                              void* d_out, int out_size, void* d_ws, size_t ws_size,
                              hipStream_t stream) {
  const float* x     = (const float*)d_in[0];
  const float* W1    = (const float*)d_in[1];
  const float* b1    = (const float*)d_in[2];
  const float* W2    = (const float*)d_in[3];
  const float* b2    = (const float*)d_in[4];
  const float* Wo    = (const float*)d_in[5];
  const float* bo    = (const float*)d_in[6];
  const float* gamma = (const float*)d_in[7];
  const float* beta  = (const float*)d_in[8];

  const int M = in_sizes[0] / HIDDEN;   // 8*4096 = 32768 tokens

  // workspace layout (bytes):
  //   [0, M*768*2)                      xb   (bf16 x)   -- reused as pred after GEMM1
  //   [M*768*2, +M*512*2)               h    (bf16)
  //   then W1b, W2b, Wob (bf16 weights)
  char* ws = (char*)d_ws;
  bf16_t* xb   = (bf16_t*)ws;
  bf16_t* pred = xb;
  bf16_t* h    = (bf16_t*)(ws + (size_t)M * HIDDEN * 2);
  bf16_t* W1b  = (bf16_t*)(ws + (size_t)M * HIDDEN * 2 + (size_t)M * INNER * 2);
  bf16_t* W2b  = W1b + INNER * HIDDEN;
  bf16_t* Wob  = W2b + HIDDEN * INNER;

  cast_bf16<<<2048, 256, 0, stream>>>((const float4*)x,  (bf16x4*)xb,  M * HIDDEN / 4);
  cast_bf16<<<96,   256, 0, stream>>>((const float4*)W1, (bf16x4*)W1b, INNER * HIDDEN / 4);
  cast_bf16<<<96,   256, 0, stream>>>((const float4*)W2, (bf16x4*)W2b, HIDDEN * INNER / 4);
  cast_bf16<<<144,  256, 0, stream>>>((const float4*)Wo, (bf16x4*)Wob, HIDDEN * HIDDEN / 4);

  gemm_bt<INNER,  HIDDEN, 0><<<(M / 128) * (INNER / 128),  256, 0, stream>>>(xb,   W1b, b1, h);
  gemm_bt<HIDDEN, INNER,  1><<<(M / 128) * (HIDDEN / 128), 256, 0, stream>>>(h,    W2b, b2, pred);
  gemm_bt<HIDDEN, HIDDEN, 2><<<(M / 128) * (HIDDEN / 128), 256, 0, stream>>>(pred, Wob, bo, d_out);

  ln_rows<<<M / 4, 256, 0, stream>>>((float*)d_out, gamma, beta, M);
}